// Round 3
// baseline (272.511 us; speedup 1.0000x reference)
//
#include <hip/hip_runtime.h>

#define HID 50
#define NMID 7
#define NT 4        // feature tiles (M dimension, 4*16 = 64 padded rows)
#define NS 2        // K chunks of 32 (K = 64 slots)
#define PT 4        // point tiles per wave (16 points each -> 64 points/wave)

// packed f16 params: Mid [L][t][s][64 lanes][8]; In [t][64][8]; Out [s][64][8]
#define MID_ELEMS (NMID * NT * NS * 64 * 8)   // 28672
#define IN_ELEMS  (NT * 64 * 8)               // 2048
#define OUT_ELEMS (NS * 64 * 8)               // 1024
#define W_HALFS   (MID_ELEMS + IN_ELEMS + OUT_ELEMS)

// 2*log2(e): folded into all tanh-layer weights. Producer bias carries a -1 so
// exp2(a-1)+0.5 = (e^{2x}+1)/2, and the epilogue stores r' = rcp(exp2(a')+0.5)
// = 2/(e^{2x}+1) = 1 - tanh(x). Consumers use W' = -W, b' = b + sum_j W_j.
#define SCALE 2.8853900817779268f

typedef _Float16 half8  __attribute__((ext_vector_type(8)));
typedef float    f32x4  __attribute__((ext_vector_type(4)));
typedef float    f32x2  __attribute__((ext_vector_type(2)));

__device__ __forceinline__ unsigned short f16hi(float w) {
    _Float16 h = (_Float16)w;                    // RNE
    return __builtin_bit_cast(unsigned short, h);
}
__device__ __forceinline__ unsigned short f16lo(float w) {
    _Float16 h = (_Float16)w;
    _Float16 l = (_Float16)(w - (float)h);
    return __builtin_bit_cast(unsigned short, l);
}

// storage slot k (0..63) -> row index. k = 32s + 8q + j maps to
// row = 16*(2s + (j>>2)) + 4q + (j&3): exactly the producing D fragment's
// per-lane layout, so activations feed the next layer with no lane movement.
__device__ __forceinline__ int kperm(int k) {
    int s = k >> 5, q = (k >> 3) & 3, j = k & 7;
    return 16 * (2 * s + (j >> 2)) + 4 * q + (j & 3);
}

// 13-slice feature map: rows 0..47 = features 0..47 (tiles 0-2),
// row 48 (t3,q0,r0) = feature 48, row 52 (t3,q1,r0) = feature 49.
__device__ __forceinline__ int rowfeat(int rw) {
    if (rw < 48) return rw;
    if (rw == 48) return 48;
    if (rw == 52) return 49;
    return -1;
}

__global__ void pack_params(const float* __restrict__ W_in, const float* __restrict__ b_in,
                            const float* __restrict__ W_mid, const float* __restrict__ b_mid,
                            const float* __restrict__ W_out, const float* __restrict__ b_out,
                            unsigned short* __restrict__ wp) {
    int e = blockIdx.x * 256 + threadIdx.x;
    if (e < MID_ELEMS) {
        // A = -(SCALE * W_mid[L])^T; bias slot = SCALE*(b + sum_j W_j) - 1
        int L = e / (NT * NS * 512), r1 = e % (NT * NS * 512);
        int t = r1 / (NS * 512),     r2 = r1 % (NS * 512);
        int s = r2 / 512,            r3 = r2 % 512;
        int l = r3 / 8,              j  = r3 % 8;
        int fo = rowfeat(t * 16 + (l & 15));
        int k  = s * 32 + ((l >> 4) << 3) + j;
        unsigned short bits = 0;
        if (fo >= 0) {
            if (k >= 62) {
                float sum = b_mid[L * HID + fo];
                for (int jj = 0; jj < HID; ++jj) sum += W_mid[(L * HID + jj) * HID + fo];
                float v = SCALE * sum - 1.0f;
                bits = (k == 62) ? f16hi(v) : f16lo(v);
            } else {
                int fi = rowfeat(kperm(k));
                if (fi >= 0) bits = f16hi(-SCALE * W_mid[(L * HID + fi) * HID + fo]);
            }
        }
        wp[e] = bits;
    } else if (e < MID_ELEMS + IN_ELEMS) {
        // input layer consumes raw x,y,z: W keeps +SCALE; bias = SCALE*b - 1.
        int e2 = e - MID_ELEMS;
        int t = e2 / 512, r = e2 % 512, l = r / 8, j = r % 8;
        int fo = rowfeat(t * 16 + (l & 15));
        int q  = l >> 4;
        unsigned short bits = 0;
        if (fo >= 0 && q == 0) {
            if (j < 3)       bits = f16hi(SCALE * W_in[j * HID + fo]);
            else if (j < 6)  bits = f16hi(SCALE * W_in[(j - 3) * HID + fo]);
            else {
                float v = SCALE * b_in[fo] - 1.0f;
                bits = (j == 6) ? f16hi(v) : f16lo(v);
            }
        }
        wp[e] = bits;
    } else if (e < W_HALFS) {
        // output layer: consumer fold only: W' = -W_out, bias = b_out + sum W.
        int e3 = e - MID_ELEMS - IN_ELEMS;
        int s = e3 / 512, r = e3 % 512, l = r / 8, j = r % 8;
        int m = l & 15;
        int k = s * 32 + ((l >> 4) << 3) + j;
        unsigned short bits = 0;
        if (m < 3) {
            if (k >= 62) {
                float sum = b_out[m];
                for (int jj = 0; jj < HID; ++jj) sum += W_out[jj * 3 + m];
                bits = (k == 62) ? f16hi(sum) : f16lo(sum);
            } else {
                int fi = rowfeat(kperm(k));
                if (fi >= 0) bits = f16hi(-W_out[fi * 3 + m]);
            }
        }
        wp[e] = bits;
    }
}

__device__ __forceinline__ unsigned int pk2(float a, float b) {
    auto p = __builtin_amdgcn_cvt_pkrtz(a, b);
    return __builtin_bit_cast(unsigned int, p);
}
// Quad epilogue with ONE shared rcp: product tree over d0..d3, each
// r_i = (prod of the others) * rcp(prod all). d <= 2^22 (|a'| bounded by
// SCALE*sum|W| ~ 22) so the 4-product <= 2^88 stays in f32 range.
// f32x2 arithmetic invites v_pk_add_f32 / v_pk_mul_f32.
__device__ __forceinline__ void rr_quad(float a0, float a1, float a2, float a3,
                                        unsigned int& u0, unsigned int& u1) {
    f32x2 e01, e23;
    e01[0] = __builtin_amdgcn_exp2f(a0);
    e01[1] = __builtin_amdgcn_exp2f(a1);
    e23[0] = __builtin_amdgcn_exp2f(a2);
    e23[1] = __builtin_amdgcn_exp2f(a3);
    f32x2 d01 = e01 + 0.5f;
    f32x2 d23 = e23 + 0.5f;
    float p01 = d01[0] * d01[1];
    float p23 = d23[0] * d23[1];
    float inv = __builtin_amdgcn_rcpf(p01 * p23);
    f32x2 i01 = {inv * p23, inv * p23};
    f32x2 i23 = {inv * p01, inv * p01};
    f32x2 r01 = i01 * __builtin_shufflevector(d01, d01, 1, 0);
    f32x2 r23 = i23 * __builtin_shufflevector(d23, d23, 1, 0);
    u0 = pk2(r01[0], r01[1]);
    u1 = pk2(r23[0], r23[1]);
}
// chunk s=0: j0..3 = tile0 rows 0..3, j4..7 = tile1 rows 0..3 (all live)
__device__ __forceinline__ half8 epi_full(const f32x4& c0, const f32x4& c1) {
    uint4 u;
    rr_quad(c0[0], c0[1], c0[2], c0[3], u.x, u.y);
    rr_quad(c1[0], c1[1], c1[2], c1[3], u.z, u.w);
    return __builtin_bit_cast(half8, u);
}
// chunk s=1: tile2 rows 0..3 live; tile3 only r=0 live (features 48/49).
// j5 dead (zero A column); j6/j7 = bias B-slots for quad 3 -> constant 1.0.
__device__ __forceinline__ half8 epi_tail(const f32x4& c2, const f32x4& c3) {
    uint4 u;
    rr_quad(c2[0], c2[1], c2[2], c2[3], u.x, u.y);
    float e = __builtin_amdgcn_exp2f(c3[0]);
    float r = __builtin_amdgcn_rcpf(e + 0.5f);
    u.z = pk2(r, 1.0f);
    u.w = 0x3C003C00u;
    return __builtin_bit_cast(half8, u);
}

__device__ __forceinline__ void mfma_mid(const half8 (&A)[NT * NS], const half8 (&Bp)[NS],
                                         f32x4 (&cc)[NT]) {
#pragma unroll
    for (int t = 0; t < NT; ++t) {
        f32x4 z4 = (f32x4){0.f, 0.f, 0.f, 0.f};
        f32x4 c = __builtin_amdgcn_mfma_f32_16x16x32_f16(A[t * NS + 0], Bp[0], z4, 0, 0, 0);
        cc[t]   = __builtin_amdgcn_mfma_f32_16x16x32_f16(A[t * NS + 1], Bp[1], c,  0, 0, 0);
    }
}

// Flipped-GEMM, fully register-resident MLP: A = folded-W^T fragments
// (M = out-features), B = r'-activations (N = points). No LDS anywhere.
// Each layer is software-pipelined: MFMA(pt+1) is issued before the
// epilogue of pt (independent: reads B[pt+1] produced last layer), and the
// next layer's A fragments are prefetched 2-at-a-time under the epilogues.
__global__ __launch_bounds__(256, 4) void softmesh_mfma(
    const float* __restrict__ x, const float* __restrict__ y,
    const float* __restrict__ z,
    const unsigned short* __restrict__ wp,
    float* __restrict__ out, int n)
{
    const int tid  = threadIdx.x;
    const int wave = tid >> 6, lane = tid & 63;
    const int m = lane & 15, quad = lane >> 4;

    const int i0 = (blockIdx.x * 4 + wave) * 64;
    if (i0 >= n) return;

    // ---- issue input loads first (cold HBM ~900cy, hide under weight loads) ----
    float xv[PT], yv[PT], zv[PT];
#pragma unroll
    for (int pt = 0; pt < PT; ++pt) {
        int idx = min(i0 + pt * 16 + m, n - 1);
        if (quad == 0) { xv[pt] = x[idx]; yv[pt] = y[idx]; zv[pt] = z[idx]; }
    }

    const half8* __restrict__ Wm = (const half8*)wp;
    const half8* __restrict__ Wi = Wm + MID_ELEMS / 8;
    const half8* __restrict__ Wo = Wi + IN_ELEMS / 8;

    half8 Ain[NT];
#pragma unroll
    for (int t = 0; t < NT; ++t) Ain[t] = Wi[t * 64 + lane];
    half8 A[NT * NS];
#pragma unroll
    for (int i = 0; i < NT * NS; ++i) A[i] = Wm[i * 64 + lane];

    half8 B[PT][NS];   // r'-activations, register-resident across all layers
    f32x4 cc0[NT], cc1[NT];

    // ---- input layer: K=32, data in octet 0 (quad-0 lanes), pipelined ----
    {
        half8 bf[PT];
#pragma unroll
        for (int pt = 0; pt < PT; ++pt) {
            half8 b8 = {0, 0, 0, 0, 0, 0, 0, 0};
            if (quad == 0) {
                _Float16 xh = (_Float16)xv[pt], yh = (_Float16)yv[pt], zh = (_Float16)zv[pt];
                b8[0] = xh; b8[1] = yh; b8[2] = zh;
                b8[3] = (_Float16)(xv[pt] - (float)xh);
                b8[4] = (_Float16)(yv[pt] - (float)yh);
                b8[5] = (_Float16)(zv[pt] - (float)zh);
                b8[6] = (_Float16)1.0f; b8[7] = (_Float16)1.0f;   // bias hi/lo
            }
            bf[pt] = b8;
        }
#pragma unroll
        for (int t = 0; t < NT; ++t) {
            f32x4 z4 = (f32x4){0.f, 0.f, 0.f, 0.f};
            cc0[t] = __builtin_amdgcn_mfma_f32_16x16x32_f16(Ain[t], bf[0], z4, 0, 0, 0);
        }
#pragma unroll
        for (int t = 0; t < NT; ++t) {
            f32x4 z4 = (f32x4){0.f, 0.f, 0.f, 0.f};
            cc1[t] = __builtin_amdgcn_mfma_f32_16x16x32_f16(Ain[t], bf[1], z4, 0, 0, 0);
        }
        B[0][0] = epi_full(cc0[0], cc0[1]); B[0][1] = epi_tail(cc0[2], cc0[3]);
#pragma unroll
        for (int t = 0; t < NT; ++t) {
            f32x4 z4 = (f32x4){0.f, 0.f, 0.f, 0.f};
            cc0[t] = __builtin_amdgcn_mfma_f32_16x16x32_f16(Ain[t], bf[2], z4, 0, 0, 0);
        }
        B[1][0] = epi_full(cc1[0], cc1[1]); B[1][1] = epi_tail(cc1[2], cc1[3]);
#pragma unroll
        for (int t = 0; t < NT; ++t) {
            f32x4 z4 = (f32x4){0.f, 0.f, 0.f, 0.f};
            cc1[t] = __builtin_amdgcn_mfma_f32_16x16x32_f16(Ain[t], bf[3], z4, 0, 0, 0);
        }
        B[2][0] = epi_full(cc0[0], cc0[1]); B[2][1] = epi_tail(cc0[2], cc0[3]);
        B[3][0] = epi_full(cc1[0], cc1[1]); B[3][1] = epi_tail(cc1[2], cc1[3]);
    }

    // ---- 7 mid layers, fully unrolled, pipelined ----
#pragma unroll
    for (int L = 0; L < NMID; ++L) {
        const bool last = (L == NMID - 1);
        half8 An[NT * NS];

        mfma_mid(A, B[0], cc0);
        if (!last) { An[0] = Wm[((L + 1) * 8 + 0) * 64 + lane];
                     An[1] = Wm[((L + 1) * 8 + 1) * 64 + lane]; }
        else       { An[0] = Wo[lane]; An[1] = Wo[64 + lane]; }

        mfma_mid(A, B[1], cc1);
        if (!last) { An[2] = Wm[((L + 1) * 8 + 2) * 64 + lane];
                     An[3] = Wm[((L + 1) * 8 + 3) * 64 + lane]; }
        else       { An[2] = A[2]; An[3] = A[3]; }   // dead
        B[0][0] = epi_full(cc0[0], cc0[1]); B[0][1] = epi_tail(cc0[2], cc0[3]);

        mfma_mid(A, B[2], cc0);
        if (!last) { An[4] = Wm[((L + 1) * 8 + 4) * 64 + lane];
                     An[5] = Wm[((L + 1) * 8 + 5) * 64 + lane]; }
        else       { An[4] = A[4]; An[5] = A[5]; }   // dead
        B[1][0] = epi_full(cc1[0], cc1[1]); B[1][1] = epi_tail(cc1[2], cc1[3]);

        mfma_mid(A, B[3], cc1);
        if (!last) { An[6] = Wm[((L + 1) * 8 + 6) * 64 + lane];
                     An[7] = Wm[((L + 1) * 8 + 7) * 64 + lane]; }
        else       { An[6] = A[6]; An[7] = A[7]; }   // dead
        B[2][0] = epi_full(cc0[0], cc0[1]); B[2][1] = epi_tail(cc0[2], cc0[3]);

        B[3][0] = epi_full(cc1[0], cc1[1]); B[3][1] = epi_tail(cc1[2], cc1[3]);
#pragma unroll
        for (int i = 0; i < NT * NS; ++i) A[i] = An[i];
    }

    // ---- output layer: rows 0..2 of tile 0 = out dims, on quad-0 lanes ----
#pragma unroll
    for (int pt = 0; pt < PT; ++pt) {
        f32x4 z4 = (f32x4){0.f, 0.f, 0.f, 0.f};
        f32x4 c = __builtin_amdgcn_mfma_f32_16x16x32_f16(A[0], B[pt][0], z4, 0, 0, 0);
        c       = __builtin_amdgcn_mfma_f32_16x16x32_f16(A[1], B[pt][1], c,  0, 0, 0);
        if (quad == 0) {
            int idx = i0 + pt * 16 + m;
            if (idx < n) {
                out[idx] = c[0];
                out[(size_t)n + idx] = c[1];
                out[2 * (size_t)n + idx] = c[2];
            }
        }
    }
}

extern "C" void kernel_launch(void* const* d_in, const int* in_sizes, int n_in,
                              void* d_out, int out_size, void* d_ws, size_t ws_size,
                              hipStream_t stream) {
    const float* x     = (const float*)d_in[0];
    const float* y     = (const float*)d_in[1];
    const float* z     = (const float*)d_in[2];
    const float* W_in  = (const float*)d_in[3];
    const float* b_in  = (const float*)d_in[4];
    const float* W_mid = (const float*)d_in[5];
    const float* b_mid = (const float*)d_in[6];
    const float* W_out = (const float*)d_in[7];
    const float* b_out = (const float*)d_in[8];
    float* out = (float*)d_out;
    int n = in_sizes[0];

    unsigned short* wpp = (unsigned short*)d_ws;

    int pgrid = (W_HALFS + 255) / 256;
    pack_params<<<pgrid, 256, 0, stream>>>(W_in, b_in, W_mid, b_mid, W_out, b_out, wpp);

    int grid = (n + 255) / 256;   // 4 waves/block, 64 points/wave
    softmesh_mfma<<<grid, 256, 0, stream>>>(x, y, z, wpp, out, n);
}